// Round 1
// baseline (321.620 us; speedup 1.0000x reference)
//
#include <hip/hip_runtime.h>

#define DEV __device__ __forceinline__

typedef _Float16 f16;
typedef __attribute__((ext_vector_type(8))) _Float16 f16x8;
typedef __attribute__((ext_vector_type(4))) float f32x4;

constexpr int B = 2, T = 2048, D = 1024, H = 16, DH = 64;
constexpr int M = B * T;  // 4096

DEV void gload_lds16(const void* g, void* l) {
  __builtin_amdgcn_global_load_lds(
      (const __attribute__((address_space(1))) void*)g,
      (__attribute__((address_space(3))) void*)l, 16, 0, 0);
}

// ---------------- cast f32 -> f16 ----------------
__global__ __launch_bounds__(256) void cast_f32_f16(
    const float* __restrict__ in, f16* __restrict__ out, int n) {
  int i = (blockIdx.x * 256 + threadIdx.x) * 8;
  if (i >= n) return;
  f32x4 a = *(const f32x4*)(in + i);
  f32x4 b = *(const f32x4*)(in + i + 4);
  f16x8 o;
  o[0] = (f16)a[0]; o[1] = (f16)a[1]; o[2] = (f16)a[2]; o[3] = (f16)a[3];
  o[4] = (f16)b[0]; o[5] = (f16)b[1]; o[6] = (f16)b[2]; o[7] = (f16)b[3];
  *(f16x8*)(out + i) = o;
}

// ---------------- transpose + cast W -> WT (WT[n][k] = W[k][n]) ----------------
__global__ __launch_bounds__(256) void transpose_cast(
    const float* __restrict__ Wq, const float* __restrict__ Wk,
    const float* __restrict__ Wv, f16* __restrict__ WT) {
  int mat = blockIdx.z;
  const float* W = (mat == 0) ? Wq : (mat == 1 ? Wk : Wv);
  f16* out = WT + (size_t)mat * D * D;
  __shared__ float tile[32][33];
  int nt = blockIdx.x * 32, kt = blockIdx.y * 32;
  int tx = threadIdx.x, ty = threadIdx.y;
  for (int j = 0; j < 4; ++j) {
    int r = ty + 8 * j;
    tile[r][tx] = W[(size_t)(kt + r) * D + nt + tx];
  }
  __syncthreads();
  for (int j = 0; j < 4; ++j) {
    int r = ty + 8 * j;
    out[(size_t)(nt + r) * D + kt + tx] = (f16)tile[tx][r];
  }
}

// ---------------- QKV projection GEMM ----------------
// out[m][n] = (sum_k X[m][k] * WT[n][k] + bias[n]) * oscale, fp16 out.
// 128x128 tile, BK=64, 4 waves (2x2), 16x16x32 f16 MFMA.
__global__ __launch_bounds__(256) void qkv_gemm(
    const f16* __restrict__ XQ, const f16* __restrict__ XK,
    const f16* __restrict__ WT, const float* __restrict__ bq,
    const float* __restrict__ bk, const float* __restrict__ bv,
    f16* __restrict__ QKV) {
  int mat = blockIdx.z;
  const f16* X = (mat == 0) ? XQ : XK;
  const f16* Wt = WT + (size_t)mat * D * D;
  const float* bias = (mat == 0) ? bq : (mat == 1 ? bk : bv);
  f16* out = QKV + (size_t)mat * M * D;
  float oscale = (mat == 0) ? 0.125f : 1.0f;  // 1/sqrt(DH) folded into Q
  int m0 = blockIdx.y * 128, n0 = blockIdx.x * 128;

  __shared__ f16 lA[128 * 64];
  __shared__ f16 lB[128 * 64];
  char* lAb = (char*)lA;
  char* lBb = (char*)lB;

  int tid = threadIdx.x;
  int w = tid >> 6, lane = tid & 63;
  int l15 = lane & 15, lhi = lane >> 4;
  int wr = w >> 1, wc = w & 1;
  int r8 = lane >> 3, slot = lane & 7;
  int sslot = slot ^ r8;  // pre-swizzled global source slot

  f32x4 acc[4][4] = {};

  for (int kt = 0; kt < D / 64; ++kt) {
    __syncthreads();
    for (int i = 0; i < 4; ++i) {
      int chunk = w * 4 + i;
      int row = chunk * 8 + r8;
      const f16* srcA = X + (size_t)(m0 + row) * D + kt * 64 + sslot * 8;
      gload_lds16(srcA, lAb + chunk * 1024);
      const f16* srcB = Wt + (size_t)(n0 + row) * D + kt * 64 + sslot * 8;
      gload_lds16(srcB, lBb + chunk * 1024);
    }
    __syncthreads();
    for (int ks = 0; ks < 2; ++ks) {
      f16x8 aF[4], bF[4];
      for (int mt = 0; mt < 4; ++mt) {
        int row = wr * 64 + mt * 16 + l15;
        int byt = row * 128 + ks * 64 + lhi * 16;
        byt ^= (row & 7) << 4;
        aF[mt] = *(const f16x8*)(lAb + byt);
      }
      for (int nt = 0; nt < 4; ++nt) {
        int row = wc * 64 + nt * 16 + l15;
        int byt = row * 128 + ks * 64 + lhi * 16;
        byt ^= (row & 7) << 4;
        bF[nt] = *(const f16x8*)(lBb + byt);
      }
      for (int mt = 0; mt < 4; ++mt)
        for (int nt = 0; nt < 4; ++nt)
          acc[mt][nt] = __builtin_amdgcn_mfma_f32_16x16x32_f16(
              aF[mt], bF[nt], acc[mt][nt], 0, 0, 0);
    }
  }

  float bv4[4];
  for (int nt = 0; nt < 4; ++nt) bv4[nt] = bias[n0 + wc * 64 + nt * 16 + l15];
  for (int mt = 0; mt < 4; ++mt)
    for (int nt = 0; nt < 4; ++nt) {
      int col = n0 + wc * 64 + nt * 16 + l15;
      for (int r = 0; r < 4; ++r) {
        int row = m0 + wr * 64 + mt * 16 + lhi * 4 + r;
        out[(size_t)row * D + col] = (f16)((acc[mt][nt][r] + bv4[nt]) * oscale);
      }
    }
}

// ---------------- fused flash attention ----------------
// grid (T/64, H, B); 256 threads = 4 waves; wave w owns q rows [w*16, w*16+16).
__global__ __launch_bounds__(256) void attn(
    const f16* __restrict__ QKV, const float* __restrict__ mask,
    const int* __restrict__ mfp, float* __restrict__ out) {
  const f16* Q = QKV;
  const f16* K = QKV + (size_t)M * D;
  const f16* V = QKV + (size_t)2 * M * D;
  int b = blockIdx.z, h = blockIdx.y, q0 = blockIdx.x * 64;
  int mf = *mfp;

  __shared__ f16 sQ[64 * 64];
  __shared__ f16 sK[64 * 64];
  __shared__ f16 sVT[64 * 64];
  __shared__ f16 sP[4][16 * 64];
  char* sQb = (char*)sQ;
  char* sKb = (char*)sK;
  char* sVb = (char*)sVT;

  int tid = threadIdx.x;
  int w = tid >> 6, lane = tid & 63;
  int l15 = lane & 15, lhi = lane >> 4;
  int r8 = lane >> 3, slot = lane & 7;
  int sslot = slot ^ r8;
  char* sPb = (char*)sP[w];

  // stage Q tile once (rows q0..q0+63, head slice)
  for (int i = 0; i < 2; ++i) {
    int chunk = w * 2 + i;
    int row = chunk * 8 + r8;
    const f16* src = Q + (size_t)(b * T + q0 + row) * D + h * 64 + sslot * 8;
    gload_lds16(src, sQb + chunk * 1024);
  }

  float mprev[4], lsum[4];
  f32x4 accO[4] = {};
  for (int r = 0; r < 4; ++r) { mprev[r] = -1e30f; lsum[r] = 0.f; }
  const float* maskb = mask + (size_t)b * T;

  for (int kv0 = 0; kv0 < T; kv0 += 64) {
    __syncthreads();  // prior-iter LDS reads done (also covers Q stage iter0)
    // stage K tile (row-major, swizzled via pre-swizzled source)
    for (int i = 0; i < 2; ++i) {
      int chunk = w * 2 + i;
      int row = chunk * 8 + r8;
      const f16* src = K + (size_t)(b * T + kv0 + row) * D + h * 64 + sslot * 8;
      gload_lds16(src, sKb + chunk * 1024);
    }
    // stage V transposed: sVT[d][kv], swizzled
    for (int c = 0; c < 2; ++c) {
      int t = tid + c * 256;
      int kvr = t >> 3, d0 = (t & 7) * 8;
      f16x8 v = *(const f16x8*)(V + (size_t)(b * T + kv0 + kvr) * D + h * 64 + d0);
      for (int j = 0; j < 8; ++j) {
        int dr = d0 + j;
        int byt = dr * 128 + kvr * 2;
        byt ^= (dr & 7) << 4;
        *(f16*)(sVb + byt) = v[j];
      }
    }
    __syncthreads();

    // QK^T : scores s[nt][r], col = kv0+nt*16+l15, row = q0+w*16+lhi*4+r
    f32x4 s[4] = {};
    for (int ks = 0; ks < 2; ++ks) {
      int qrow = w * 16 + l15;
      int abyte = qrow * 128 + ks * 64 + lhi * 16;
      abyte ^= (qrow & 7) << 4;
      f16x8 aF = *(const f16x8*)(sQb + abyte);
      for (int nt = 0; nt < 4; ++nt) {
        int krow = nt * 16 + l15;
        int bbyte = krow * 128 + ks * 64 + lhi * 16;
        bbyte ^= (krow & 7) << 4;
        f16x8 bF = *(const f16x8*)(sKb + bbyte);
        s[nt] = __builtin_amdgcn_mfma_f32_16x16x32_f16(aF, bF, s[nt], 0, 0, 0);
      }
    }

    // mask + online softmax (scale already folded into Q)
    float rmax[4] = {-1e30f, -1e30f, -1e30f, -1e30f};
    for (int nt = 0; nt < 4; ++nt) {
      int col = kv0 + nt * 16 + l15;
      float mc = maskb[col];
      for (int r = 0; r < 4; ++r) {
        float v = s[nt][r] + mc;
        if (mf && col >= q0 + w * 16 + lhi * 4 + r) v = -1e30f;
        s[nt][r] = v;
        rmax[r] = fmaxf(rmax[r], v);
      }
    }
    for (int r = 0; r < 4; ++r) {
      float m = rmax[r];
      m = fmaxf(m, __shfl_xor(m, 1, 64));
      m = fmaxf(m, __shfl_xor(m, 2, 64));
      m = fmaxf(m, __shfl_xor(m, 4, 64));
      m = fmaxf(m, __shfl_xor(m, 8, 64));
      rmax[r] = m;
    }
    float asc[4];
    for (int r = 0; r < 4; ++r) {
      float mnew = fmaxf(mprev[r], rmax[r]);
      asc[r] = __expf(mprev[r] - mnew);
      mprev[r] = mnew;
    }
    float rsum[4] = {};
    for (int nt = 0; nt < 4; ++nt)
      for (int r = 0; r < 4; ++r) {
        float p = __expf(s[nt][r] - mprev[r]);
        s[nt][r] = p;
        rsum[r] += p;
      }
    for (int r = 0; r < 4; ++r) {
      float sum = rsum[r];
      sum += __shfl_xor(sum, 1, 64);
      sum += __shfl_xor(sum, 2, 64);
      sum += __shfl_xor(sum, 4, 64);
      sum += __shfl_xor(sum, 8, 64);
      lsum[r] = lsum[r] * asc[r] + sum;
    }
    for (int dt = 0; dt < 4; ++dt)
      for (int r = 0; r < 4; ++r) accO[dt][r] *= asc[r];

    // P -> LDS (fp16, swizzled), per-wave region
    for (int nt = 0; nt < 4; ++nt)
      for (int r = 0; r < 4; ++r) {
        int row = lhi * 4 + r;
        int byt = row * 128 + (nt * 16 + l15) * 2;
        byt ^= (row & 7) << 4;
        *(f16*)(sPb + byt) = (f16)s[nt][r];
      }
    __syncthreads();

    // PV: accO[dt] += P[16 x 64] * V[64 x 64]
    for (int ks = 0; ks < 2; ++ks) {
      int prow = l15;
      int pbyte = prow * 128 + ks * 64 + lhi * 16;
      pbyte ^= (prow & 7) << 4;
      f16x8 pF = *(const f16x8*)(sPb + pbyte);
      for (int dt = 0; dt < 4; ++dt) {
        int vrow = dt * 16 + l15;
        int vbyte = vrow * 128 + ks * 64 + lhi * 16;
        vbyte ^= (vrow & 7) << 4;
        f16x8 vF = *(const f16x8*)(sVb + vbyte);
        accO[dt] = __builtin_amdgcn_mfma_f32_16x16x32_f16(pF, vF, accO[dt], 0, 0, 0);
      }
    }
  }

  for (int r = 0; r < 4; ++r) lsum[r] = 1.0f / lsum[r];
  for (int dt = 0; dt < 4; ++dt)
    for (int r = 0; r < 4; ++r) {
      int qrow = q0 + w * 16 + lhi * 4 + r;
      int d = dt * 16 + l15;
      out[(size_t)(b * T + qrow) * D + h * 64 + d] = accO[dt][r] * lsum[r];
    }
}

extern "C" void kernel_launch(void* const* d_in, const int* in_sizes, int n_in,
                              void* d_out, int out_size, void* d_ws, size_t ws_size,
                              hipStream_t stream) {
  const float* q_in = (const float*)d_in[0];
  const float* k_in = (const float*)d_in[1];
  const float* amask = (const float*)d_in[2];
  const float* Wq = (const float*)d_in[3];
  const float* bq = (const float*)d_in[4];
  const float* Wk = (const float*)d_in[5];
  const float* bk = (const float*)d_in[6];
  const float* Wv = (const float*)d_in[7];
  const float* bv = (const float*)d_in[8];
  const int* mf = (const int*)d_in[9];
  float* out = (float*)d_out;

  char* ws = (char*)d_ws;
  f16* XQ = (f16*)ws;                       // 8 MB
  f16* XK = (f16*)(ws + 8388608);           // 8 MB
  f16* WT = (f16*)(ws + 16777216);          // 6 MB (3 x 2MB)
  f16* QKV = (f16*)(ws + 23068672);         // 24 MB (Q,K,V fp16)

  cast_f32_f16<<<2048, 256, 0, stream>>>(q_in, XQ, M * D);
  cast_f32_f16<<<2048, 256, 0, stream>>>(k_in, XK, M * D);
  transpose_cast<<<dim3(32, 32, 3), dim3(32, 8), 0, stream>>>(Wq, Wk, Wv, WT);
  qkv_gemm<<<dim3(8, 32, 3), 256, 0, stream>>>(XQ, XK, WT, bq, bk, bv, QKV);
  attn<<<dim3(32, 16, 2), 256, 0, stream>>>(QKV, amask, mf, out);
}

// Round 3
// 213.117 us; speedup vs baseline: 1.5091x; 1.5091x over previous
//
#include <hip/hip_runtime.h>

#define DEV __device__ __forceinline__

typedef _Float16 f16;
typedef __attribute__((ext_vector_type(2))) _Float16 f16x2;
typedef __attribute__((ext_vector_type(8))) _Float16 f16x8;
typedef __attribute__((ext_vector_type(4))) float f32x4;
typedef __attribute__((ext_vector_type(16))) float f32x16;

constexpr int B = 2, T = 2048, D = 1024, H = 16, DH = 64;
constexpr int M = B * T;  // 4096
constexpr float LOG2E = 1.4426950408889634f;

DEV void gload_lds16(const void* g, void* l) {
  __builtin_amdgcn_global_load_lds(
      (const __attribute__((address_space(1))) void*)g,
      (__attribute__((address_space(3))) void*)l, 16, 0, 0);
}

DEV unsigned pack_pk(float a, float b) {
  auto v = __builtin_amdgcn_cvt_pkrtz(a, b);
  return __builtin_bit_cast(unsigned, v);
}

// ---------------- cast f32 -> f16 ----------------
__global__ __launch_bounds__(256) void cast_f32_f16(
    const float* __restrict__ in, f16* __restrict__ out, int n) {
  int i = (blockIdx.x * 256 + threadIdx.x) * 8;
  if (i >= n) return;
  f32x4 a = *(const f32x4*)(in + i);
  f32x4 b = *(const f32x4*)(in + i + 4);
  f16x8 o;
  o[0] = (f16)a[0]; o[1] = (f16)a[1]; o[2] = (f16)a[2]; o[3] = (f16)a[3];
  o[4] = (f16)b[0]; o[5] = (f16)b[1]; o[6] = (f16)b[2]; o[7] = (f16)b[3];
  *(f16x8*)(out + i) = o;
}

// ---------------- transpose + cast W -> WT (WT[n][k] = W[k][n]) ----------------
__global__ __launch_bounds__(256) void transpose_cast(
    const float* __restrict__ Wq, const float* __restrict__ Wk,
    const float* __restrict__ Wv, f16* __restrict__ WT) {
  int mat = blockIdx.z;
  const float* W = (mat == 0) ? Wq : (mat == 1 ? Wk : Wv);
  f16* out = WT + (size_t)mat * D * D;
  __shared__ float tile[32][33];
  int nt = blockIdx.x * 32, kt = blockIdx.y * 32;
  int tx = threadIdx.x, ty = threadIdx.y;
  for (int j = 0; j < 4; ++j) {
    int r = ty + 8 * j;
    tile[r][tx] = W[(size_t)(kt + r) * D + nt + tx];
  }
  __syncthreads();
  for (int j = 0; j < 4; ++j) {
    int r = ty + 8 * j;
    out[(size_t)(nt + r) * D + kt + tx] = (f16)tile[tx][r];
  }
}

// ---------------- QKV projection GEMM ----------------
__global__ __launch_bounds__(256) void qkv_gemm(
    const f16* __restrict__ XQ, const f16* __restrict__ XK,
    const f16* __restrict__ WT, const float* __restrict__ bq,
    const float* __restrict__ bk, const float* __restrict__ bv,
    f16* __restrict__ QKV) {
  int mat = blockIdx.z;
  const f16* X = (mat == 0) ? XQ : XK;
  const f16* Wt = WT + (size_t)mat * D * D;
  const float* bias = (mat == 0) ? bq : (mat == 1 ? bk : bv);
  f16* out = QKV + (size_t)mat * M * D;
  float oscale = (mat == 0) ? 0.125f * LOG2E : 1.0f;  // 1/sqrt(DH)*log2e into Q
  int m0 = blockIdx.y * 128, n0 = blockIdx.x * 128;

  __shared__ f16 lA[128 * 64];
  __shared__ f16 lB[128 * 64];
  char* lAb = (char*)lA;
  char* lBb = (char*)lB;

  int tid = threadIdx.x;
  int w = tid >> 6, lane = tid & 63;
  int l15 = lane & 15, lhi = lane >> 4;
  int wr = w >> 1, wc = w & 1;
  int r8 = lane >> 3, slot = lane & 7;
  int sslot = slot ^ r8;

  f32x4 acc[4][4] = {};

  for (int kt = 0; kt < D / 64; ++kt) {
    __syncthreads();
    for (int i = 0; i < 4; ++i) {
      int chunk = w * 4 + i;
      int row = chunk * 8 + r8;
      const f16* srcA = X + (size_t)(m0 + row) * D + kt * 64 + sslot * 8;
      gload_lds16(srcA, lAb + chunk * 1024);
      const f16* srcB = Wt + (size_t)(n0 + row) * D + kt * 64 + sslot * 8;
      gload_lds16(srcB, lBb + chunk * 1024);
    }
    __syncthreads();
    for (int ks = 0; ks < 2; ++ks) {
      f16x8 aF[4], bF[4];
      for (int mt = 0; mt < 4; ++mt) {
        int row = wr * 64 + mt * 16 + l15;
        int byt = row * 128 + ks * 64 + lhi * 16;
        byt ^= (row & 7) << 4;
        aF[mt] = *(const f16x8*)(lAb + byt);
      }
      for (int nt = 0; nt < 4; ++nt) {
        int row = wc * 64 + nt * 16 + l15;
        int byt = row * 128 + ks * 64 + lhi * 16;
        byt ^= (row & 7) << 4;
        bF[nt] = *(const f16x8*)(lBb + byt);
      }
      for (int mt = 0; mt < 4; ++mt)
        for (int nt = 0; nt < 4; ++nt)
          acc[mt][nt] = __builtin_amdgcn_mfma_f32_16x16x32_f16(
              aF[mt], bF[nt], acc[mt][nt], 0, 0, 0);
    }
  }

  float bv4[4];
  for (int nt = 0; nt < 4; ++nt) bv4[nt] = bias[n0 + wc * 64 + nt * 16 + l15];
  for (int mt = 0; mt < 4; ++mt)
    for (int nt = 0; nt < 4; ++nt) {
      int col = n0 + wc * 64 + nt * 16 + l15;
      for (int r = 0; r < 4; ++r) {
        int row = m0 + wr * 64 + mt * 16 + lhi * 4 + r;
        out[(size_t)row * D + col] = (f16)((acc[mt][nt][r] + bv4[nt]) * oscale);
      }
    }
}

// ---------------- V -> VT[b][h][d][t] (one-time transpose) ----------------
__global__ __launch_bounds__(256) void transpose_v(
    const f16* __restrict__ QKV, f16* __restrict__ VT) {
  const f16* V = QKV + (size_t)2 * M * D;
  int b = blockIdx.z, h = blockIdx.y, t0 = blockIdx.x * 64;
  __shared__ unsigned tl[64 * 32];
  char* tb = (char*)tl;
  int tid = threadIdx.x;
  int rp = tid >> 3, d0 = (tid & 7) * 8;
  const f16* src = V + (size_t)(b * T + t0 + 2 * rp) * D + h * 64 + d0;
  f16x8 a = *(const f16x8*)(src);
  f16x8 c = *(const f16x8*)(src + D);
#pragma unroll
  for (int j = 0; j < 8; ++j) {
    int d = d0 + j;
    f16x2 pr; pr[0] = a[j]; pr[1] = c[j];
    unsigned pk = __builtin_bit_cast(unsigned, pr);
    int byt = (d * 128 + rp * 4) ^ (((d >> 3) & 3) << 5);
    *(unsigned*)(tb + byt) = pk;
  }
  __syncthreads();
  int d = tid >> 2, c2 = tid & 3;
  int rbase = (d * 128 + c2 * 32) ^ (((d >> 3) & 3) << 5);
  uint4 x = *(uint4*)(tb + rbase);
  uint4 y = *(uint4*)(tb + rbase + 16);
  f16* dst = VT + ((size_t)(b * H + h) * 64 + d) * T + t0 + c2 * 16;
  *(uint4*)(dst) = x;
  *(uint4*)(dst + 8) = y;
}

// ---------------- fused flash attention ----------------
// grid (T/128, H, B); 256 threads = 4 waves; wave w owns q rows [w*32, w*32+32).
// Swapped-operand: S^T = mfma(K,Q) -> lane owns q = lane&31 row; softmax in-reg.
__global__ __launch_bounds__(256, 2) void attn(
    const f16* __restrict__ QKV, const f16* __restrict__ VT,
    const float* __restrict__ mask, const int* __restrict__ mfp,
    float* __restrict__ out) {
  const f16* Q = QKV;
  const f16* K = QKV + (size_t)M * D;
  int b = blockIdx.z, h = blockIdx.y, q0 = blockIdx.x * 128;
  int mf = *mfp;
  constexpr int NT = T / 64;

  __shared__ f16 sK[2][64 * 64];
  __shared__ f16 sVT[2][64 * 64];
  __shared__ f16 sP[4][32 * 64];
  __shared__ float sMask[T];
  __shared__ int sMnz;

  int tid = threadIdx.x;
  int w = tid >> 6, lane = tid & 63;
  int l31 = lane & 31, hi = lane >> 5, l7 = lane & 7;
  int qrow = q0 + w * 32 + l31;  // this lane's q row
  char* sPw = (char*)sP[w];

  // ---- mask staging (x log2e) + nonzero flag ----
  if (tid == 0) sMnz = 0;
  const float* mb = mask + (size_t)b * T;
  bool lnz = false;
#pragma unroll
  for (int i = 0; i < 2; ++i) {
    int idx = (tid + i * 256) * 4;
    f32x4 mv = *(const f32x4*)(mb + idx);
    f32x4 ms;
#pragma unroll
    for (int j = 0; j < 4; ++j) {
      ms[j] = mv[j] * LOG2E;
      lnz |= (mv[j] != 0.f);
    }
    *(f32x4*)(sMask + idx) = ms;
  }

  // ---- Q fragments in registers (once) ----
  f16x8 qF[4];
  const f16* qp = Q + (size_t)(b * T + qrow) * D + h * 64;
#pragma unroll
  for (int kc = 0; kc < 4; ++kc) qF[kc] = *(const f16x8*)(qp + kc * 16 + hi * 8);

  // ---- staging: K row-major + VT row-major, pre-swizzled source ----
  auto STAGE = [&](int kv0, int buf) {
    char* dK = (char*)sK[buf];
    char* dV = (char*)sVT[buf];
#pragma unroll
    for (int i = 0; i < 2; ++i) {
      int c = (w * 2 + i) * 64 + lane;
      int r = c >> 3;
      int slot = (c & 7) ^ (r & 7);
      const f16* srcK = K + (size_t)(b * T + kv0 + r) * D + h * 64 + slot * 8;
      gload_lds16(srcK, dK + (w * 2 + i) * 1024);
      const f16* srcV = VT + ((size_t)(b * H + h) * 64 + r) * T + kv0 + slot * 8;
      gload_lds16(srcV, dV + (w * 2 + i) * 1024);
    }
  };

  float mprev = -1e30f, lsum = 0.f;
  f32x16 oAcc[2] = {};

  __syncthreads();  // mask stores + sMnz init visible
  if (lnz) sMnz = 1;
  STAGE(0, 0);
  __syncthreads();  // flag visible; tile 0 staged (vmcnt drained)
  int domask = sMnz | mf;

  for (int t = 0; t < NT; ++t) {
    if (t) __syncthreads();  // tile t staged; prior reads done
    if (t + 1 < NT) STAGE((t + 1) * 64, (t + 1) & 1);
    int kv0 = t * 64;
    char* bK = (char*)sK[t & 1];
    char* bV = (char*)sVT[t & 1];

    // ---- QK^T: S^T frags, lane owns q-row = l31 ----
    f32x16 sA[2] = {};
#pragma unroll
    for (int f = 0; f < 2; ++f) {
#pragma unroll
      for (int kc = 0; kc < 4; ++kc) {
        int row = f * 32 + l31;
        f16x8 kF = *(const f16x8*)(bK + ((row * 128 + kc * 32 + hi * 16) ^ (l7 << 4)));
        sA[f] = __builtin_amdgcn_mfma_f32_32x32x16_f16(kF, qF[kc], sA[f], 0, 0, 0);
      }
    }

    // ---- mask + causal + row max ----
    float mx = -1e30f;
    if (domask) {
#pragma unroll
      for (int f = 0; f < 2; ++f)
#pragma unroll
        for (int r = 0; r < 16; ++r) {
          int kv = kv0 + f * 32 + (r & 3) + 8 * (r >> 2) + 4 * hi;
          float v = sA[f][r] + sMask[kv];
          if (mf && kv >= qrow) v = -1e30f;
          sA[f][r] = v;
          mx = fmaxf(mx, v);
        }
    } else {
#pragma unroll
      for (int f = 0; f < 2; ++f)
#pragma unroll
        for (int r = 0; r < 16; ++r) mx = fmaxf(mx, sA[f][r]);
    }
    mx = fmaxf(mx, __shfl_xor(mx, 32, 64));

    // ---- defer-max rescale (THR=8 in log2 domain) ----
    if (!__all(mx <= mprev + 8.f)) {
      float mn = fmaxf(mprev, mx);
      float asc = __builtin_amdgcn_exp2f(mprev - mn);
      lsum *= asc;
#pragma unroll
      for (int f = 0; f < 2; ++f)
#pragma unroll
        for (int r = 0; r < 16; ++r) oAcc[f][r] *= asc;
      mprev = mn;
    }

    // ---- exp2 + row sum ----
    float rs = 0.f;
#pragma unroll
    for (int f = 0; f < 2; ++f)
#pragma unroll
      for (int r = 0; r < 16; ++r) {
        float e = __builtin_amdgcn_exp2f(sA[f][r] - mprev);
        sA[f][r] = e;
        rs += e;
      }
    rs += __shfl_xor(rs, 32, 64);
    lsum += rs;

    // ---- P -> per-wave LDS (packed fp16, conflict-free b64 writes) ----
#pragma unroll
    for (int f = 0; f < 2; ++f)
#pragma unroll
      for (int g = 0; g < 4; ++g) {
        int byt = (l31 * 128 + f * 64 + g * 16 + hi * 8) ^ (l7 << 4);
        uint2 u;
        u.x = pack_pk(sA[f][g * 4 + 0], sA[f][g * 4 + 1]);
        u.y = pack_pk(sA[f][g * 4 + 2], sA[f][g * 4 + 3]);
        *(uint2*)(sPw + byt) = u;
      }

    // ---- PV: O^T frags = mfma(VT-frag, P-frag) ----
    f16x8 pF[4];
#pragma unroll
    for (int kc = 0; kc < 4; ++kc)
      pF[kc] = *(const f16x8*)(sPw + ((l31 * 128 + kc * 32 + hi * 16) ^ (l7 << 4)));
#pragma unroll
    for (int df = 0; df < 2; ++df)
#pragma unroll
      for (int kc = 0; kc < 4; ++kc) {
        int row = df * 32 + l31;
        f16x8 vF = *(const f16x8*)(bV + ((row * 128 + kc * 32 + hi * 16) ^ (l7 << 4)));
        oAcc[df] = __builtin_amdgcn_mfma_f32_32x32x16_f16(vF, pF[kc], oAcc[df], 0, 0, 0);
      }
  }

  // ---- epilogue: O^T -> out ----
  float linv = 1.0f / lsum;
  float* op = out + (size_t)(b * T + qrow) * D + h * 64;
#pragma unroll
  for (int df = 0; df < 2; ++df)
#pragma unroll
    for (int g = 0; g < 4; ++g) {
      f32x4 ov;
#pragma unroll
      for (int r2 = 0; r2 < 4; ++r2) ov[r2] = oAcc[df][g * 4 + r2] * linv;
      *(f32x4*)(op + df * 32 + g * 8 + hi * 4) = ov;
    }
}

extern "C" void kernel_launch(void* const* d_in, const int* in_sizes, int n_in,
                              void* d_out, int out_size, void* d_ws, size_t ws_size,
                              hipStream_t stream) {
  const float* q_in = (const float*)d_in[0];
  const float* k_in = (const float*)d_in[1];
  const float* amask = (const float*)d_in[2];
  const float* Wq = (const float*)d_in[3];
  const float* bq = (const float*)d_in[4];
  const float* Wk = (const float*)d_in[5];
  const float* bk = (const float*)d_in[6];
  const float* Wv = (const float*)d_in[7];
  const float* bv = (const float*)d_in[8];
  const int* mf = (const int*)d_in[9];
  float* out = (float*)d_out;

  char* ws = (char*)d_ws;
  f16* XQ = (f16*)ws;                            // 8 MB
  f16* XK = (f16*)(ws + (((size_t)8) << 20));    // 8 MB
  f16* WT = (f16*)(ws + (((size_t)16) << 20));   // 6 MB
  f16* QKV = (f16*)(ws + (((size_t)24) << 20));  // 24 MB (Q,K,V fp16)
  f16* VT = (f16*)(ws + (((size_t)48) << 20));   // 8 MB

  cast_f32_f16<<<2048, 256, 0, stream>>>(q_in, XQ, M * D);
  cast_f32_f16<<<2048, 256, 0, stream>>>(k_in, XK, M * D);
  transpose_cast<<<dim3(32, 32, 3), dim3(32, 8), 0, stream>>>(Wq, Wk, Wv, WT);
  qkv_gemm<<<dim3(8, 32, 3), 256, 0, stream>>>(XQ, XK, WT, bq, bk, bv, QKV);
  transpose_v<<<dim3(32, 16, 2), 256, 0, stream>>>(QKV, VT);
  attn<<<dim3(16, 16, 2), 256, 0, stream>>>(QKV, VT, amask, mf, out);
}